// Round 1
// baseline (38.392 us; speedup 1.0000x reference)
//
#include <hip/hip_runtime.h>
#include <math.h>

// RandISH: out[b, 2n+0] = Al(deg_n, kappa_b) * y0_norm[n] * Legendre_series(ct)
//          out[b, 2n+1] = Al * coeff_scale[n] * sin(theta)^deg * cos(deg*phi)
// where rv = vec[b] @ M[n], ct = cos(theta) = rz/|rv|,
// and sin^d(theta)*cos(d*phi) = (-1)^d * Re[(rx_hat + i*ry_hat)^d]  (no trig needed).

#define NBASIS 32
#define PLEN 10
#define EPSV 1e-8f

__global__ __launch_bounds__(256) void randish_kernel(
    const float* __restrict__ vec,        // (B,3)
    const float* __restrict__ rough,      // (B,)
    const float* __restrict__ mats,       // (32,3,3)
    const float* __restrict__ coeffs,     // (32,10) increasing power
    const float* __restrict__ cscale,     // (32,)
    const float* __restrict__ y0n,        // (32,)
    const int*   __restrict__ degs,       // (32,)
    float* __restrict__ out,              // (B,64)
    int total)                            // B*32
{
    const int tid = blockIdx.x * blockDim.x + threadIdx.x;
    const int stride = gridDim.x * blockDim.x;   // multiple of 256 -> n invariant
    const int n = tid & 31;

    // per-n constants, loaded once (n is loop-invariant)
    const float m00 = mats[n * 9 + 0], m01 = mats[n * 9 + 1], m02 = mats[n * 9 + 2];
    const float m10 = mats[n * 9 + 3], m11 = mats[n * 9 + 4], m12 = mats[n * 9 + 5];
    const float m20 = mats[n * 9 + 6], m21 = mats[n * 9 + 7], m22 = mats[n * 9 + 8];
    float c[PLEN];
#pragma unroll
    for (int p = 0; p < PLEN; ++p) c[p] = coeffs[n * PLEN + p];
    const int   deg  = degs[n];
    float       cs   = cscale[n];
    if (deg & 1) cs = -cs;                         // (-1)^deg folded in
    const float y0norm = y0n[n];
    const float cdd  = (float)(deg * (deg + 1));

    for (int t = tid; t < total; t += stride) {
        const int b = t >> 5;
        const float v0 = vec[b * 3 + 0];
        const float v1 = vec[b * 3 + 1];
        const float v2 = vec[b * 3 + 2];
        const float r  = rough[b];

        // Al exponent scale: kappa = 1/(r+eps); tt = 0.5/(kappa+eps)
        const float kappa = 1.0f / (r + EPSV);
        const float tt    = 0.5f / (kappa + EPSV);

        // rotate: rv_j = sum_i v_i * M[i][j]
        const float rx = v0 * m00 + v1 * m10 + v2 * m20;
        const float ry = v0 * m01 + v1 * m11 + v2 * m21;
        const float rz = v0 * m02 + v1 * m12 + v2 * m22;

        const float rn = rsqrtf(rx * rx + ry * ry + rz * rz);
        const float xh = rx * rn;
        const float yh = ry * rn;
        const float ct = rz * rn;                  // cos(theta)

        // Legendre power series (Horner over padded coeffs)
        float v = c[PLEN - 1];
#pragma unroll
        for (int p = PLEN - 2; p >= 0; --p) v = fmaf(v, ct, c[p]);
        const float y0 = y0norm * v;

        // Re[(xh + i*yh)^deg] via complex multiply chain (deg in [1,9])
        float re = xh, im = yh;
        for (int i = 1; i < deg; ++i) {
            const float nre = re * xh - im * yh;
            im = re * yh + im * xh;
            re = nre;
        }
        const float yl1 = cs * re;

        const float al = __expf(-cdd * tt);

        float2 o;
        o.x = al * y0;
        o.y = al * yl1;
        reinterpret_cast<float2*>(out)[t] = o;
    }
}

extern "C" void kernel_launch(void* const* d_in, const int* in_sizes, int n_in,
                              void* d_out, int out_size, void* d_ws, size_t ws_size,
                              hipStream_t stream) {
    const float* vec    = (const float*)d_in[0];
    const float* rough  = (const float*)d_in[1];
    const float* mats   = (const float*)d_in[2];
    const float* coeffs = (const float*)d_in[3];
    const float* cscale = (const float*)d_in[4];
    const float* y0n    = (const float*)d_in[5];
    const int*   degs   = (const int*)d_in[6];
    float* out = (float*)d_out;

    const int B = in_sizes[1];          // roughness element count
    const int total = B * NBASIS;       // one thread per (b, n)

    const int block = 256;
    int grid = (total + block - 1) / block;
    if (grid > 4096) grid = 4096;       // grid-stride the rest

    randish_kernel<<<grid, block, 0, stream>>>(vec, rough, mats, coeffs, cscale,
                                               y0n, degs, out, total);
}

// Round 2
// 26.030 us; speedup vs baseline: 1.4749x; 1.4749x over previous
//
#include <hip/hip_runtime.h>
#include <math.h>

// RandISH: out[b, 2n+0] = Al(deg_n, kappa_b) * y0_norm[n] * Legendre_l(ct)
//          out[b, 2n+1] = Al * coeff_scale[n] * sin(theta)^deg * cos(deg*phi)
// rv = vec[b] @ M[n] (rotation, |vec|=1 -> |rv|=1, no normalization needed)
// ct = cos(theta) = rz ;  sin^d(theta)*cos(d*phi) = (-1)^d * Re[(rx + i*ry)^d]
// Al = exp(-0.5*d(d+1)*(r+eps))  (exact to 1e-8 rel: 0.5/(1/(r+e)+e) ~= 0.5(r+e))

#define NBASIS 32
#define PLEN 10
#define EPSV 1e-8f

__global__ __launch_bounds__(256) void randish_kernel(
    const float* __restrict__ vec,        // (B,3)
    const float* __restrict__ rough,      // (B,)
    const float* __restrict__ mats,       // (32,3,3)
    const float* __restrict__ coeffs,     // (32,10) increasing power
    const float* __restrict__ cscale,     // (32,)
    const float* __restrict__ y0n,        // (32,)
    const int*   __restrict__ degs,       // (32,)
    float* __restrict__ out,              // (B,64)
    int total)                            // B*32
{
    const int tid = blockIdx.x * blockDim.x + threadIdx.x;
    const int stride = gridDim.x * blockDim.x;   // multiple of 256 -> n invariant
    const int n = tid & 31;

    // ---- per-n constants, loop-invariant (loaded once per thread) ----
    const float m00 = mats[n * 9 + 0], m01 = mats[n * 9 + 1], m02 = mats[n * 9 + 2];
    const float m10 = mats[n * 9 + 3], m11 = mats[n * 9 + 4], m12 = mats[n * 9 + 5];
    const float m20 = mats[n * 9 + 6], m21 = mats[n * 9 + 7], m22 = mats[n * 9 + 8];

    const int  deg = degs[n];
    const int  par = deg & 1;
    // parity-compressed Legendre coeffs: P_l has definite parity, so only
    // coeffs[par + 2k] are nonzero -> 5-term Horner in ct^2
    float h[5];
#pragma unroll
    for (int k = 0; k < 5; ++k) {
        const int idx = par + 2 * k;
        h[k] = (idx < PLEN) ? coeffs[n * PLEN + idx] : 0.0f;
    }

    float cs = cscale[n];
    if (par) cs = -cs;                               // fold (-1)^deg
    const float y0norm = y0n[n];
    const float negc   = -0.5f * (float)(deg * (deg + 1));

    // loop-invariant predicate bits for binary exponentiation (hoisted cmps)
    const bool b0 = (deg & 1) != 0;
    const bool b1 = (deg & 2) != 0;
    const bool b2 = (deg & 4) != 0;
    const bool b3 = (deg & 8) != 0;

    for (int t = tid; t < total; t += stride) {
        const int b = t >> 5;
        const float v0 = vec[b * 3 + 0];
        const float v1 = vec[b * 3 + 1];
        const float v2 = vec[b * 3 + 2];
        const float r  = rough[b];

        // rotate (|rv| == 1): rv_j = sum_i v_i * M[i][j]
        const float xh = v0 * m00 + v1 * m10 + v2 * m20;
        const float yh = v0 * m01 + v1 * m11 + v2 * m21;
        const float ct = v0 * m02 + v1 * m12 + v2 * m22;   // cos(theta)

        // Legendre series: v = ct^par * H(ct^2)
        const float ct2 = ct * ct;
        float v = h[4];
        v = fmaf(v, ct2, h[3]);
        v = fmaf(v, ct2, h[2]);
        v = fmaf(v, ct2, h[1]);
        v = fmaf(v, ct2, h[0]);
        if (par) v *= ct;                      // uniform-per-thread predicate
        const float y0 = y0norm * v;

        // Re[(xh + i*yh)^deg] via branch-free binary exponentiation
        const float s2r = fmaf(xh, xh, -(yh * yh));
        const float s2i = (xh + xh) * yh;
        const float s4r = fmaf(s2r, s2r, -(s2i * s2i));
        const float s4i = (s2r + s2r) * s2i;
        const float s8r = fmaf(s4r, s4r, -(s4i * s4i));
        const float s8i = (s4r + s4r) * s4i;

        float ar = b0 ? xh : 1.0f;
        float ai = b0 ? yh : 0.0f;
        {
            const float nr = fmaf(ar, s2r, -(ai * s2i));
            const float ni = fmaf(ar, s2i,  ai * s2r);
            ar = b1 ? nr : ar;  ai = b1 ? ni : ai;
        }
        {
            const float nr = fmaf(ar, s4r, -(ai * s4i));
            const float ni = fmaf(ar, s4i,  ai * s4r);
            ar = b2 ? nr : ar;  ai = b2 ? ni : ai;
        }
        {
            const float nr = fmaf(ar, s8r, -(ai * s8i));
            const float ni = fmaf(ar, s8i,  ai * s8r);
            ar = b3 ? nr : ar;  ai = b3 ? ni : ai;
        }
        const float yl1 = cs * ar;

        // Al = exp(-0.5*d(d+1)*(r+eps))
        const float al = __expf(negc * (r + EPSV));

        float2 o;
        o.x = al * y0;
        o.y = al * yl1;
        reinterpret_cast<float2*>(out)[t] = o;
    }
}

extern "C" void kernel_launch(void* const* d_in, const int* in_sizes, int n_in,
                              void* d_out, int out_size, void* d_ws, size_t ws_size,
                              hipStream_t stream) {
    const float* vec    = (const float*)d_in[0];
    const float* rough  = (const float*)d_in[1];
    const float* mats   = (const float*)d_in[2];
    const float* coeffs = (const float*)d_in[3];
    const float* cscale = (const float*)d_in[4];
    const float* y0n    = (const float*)d_in[5];
    const int*   degs   = (const int*)d_in[6];
    float* out = (float*)d_out;

    const int B = in_sizes[1];          // roughness element count
    const int total = B * NBASIS;       // one thread per (b, n)

    const int block = 256;
    int grid = (total + block - 1) / block;
    if (grid > 4096) grid = 4096;       // grid-stride the rest

    randish_kernel<<<grid, block, 0, stream>>>(vec, rough, mats, coeffs, cscale,
                                               y0n, degs, out, total);
}